// Round 3
// baseline (422.355 us; speedup 1.0000x reference)
//
#include <hip/hip_runtime.h>
#include <hip/hip_bf16.h>
#include <stdint.h>

typedef _Float16 f16;
typedef _Float16 f16x8 __attribute__((ext_vector_type(8)));
typedef _Float16 f16x4 __attribute__((ext_vector_type(4)));
typedef float f32x4 __attribute__((ext_vector_type(4)));

constexpr int B = 64, S = 197, HID = 768, NH = 12, DH = 64;
constexpr int M = B * S;          // 12608
constexpr int Mpad = 12672;       // 99*128
constexpr int BNS = B * NH * S;   // 151296
constexpr int VSTRIDE = 224;      // 7*32 >= 197
constexpr size_t NPH = (size_t)Mpad * HID;
constexpr size_t WSZ1 = (size_t)HID * HID;
constexpr size_t VTSZ = (size_t)B * NH * DH * VSTRIDE;

__device__ __forceinline__ f32x4 mfma16(f16x8 a, f16x8 b, f32x4 c) {
  return __builtin_amdgcn_mfma_f32_16x16x32_f16(a, b, c, 0, 0, 0);
}

__device__ __forceinline__ void gload16(const void* g, void* l) {
  __builtin_amdgcn_global_load_lds(
      (const __attribute__((address_space(1))) void*)g,
      (__attribute__((address_space(3))) void*)l, 16, 0, 0);
}

// bijective XCD-aware swizzle (m204)
__device__ __forceinline__ int xcd_swizzle(int wg, int nwg) {
  const int q = nwg >> 3, r = nwg & 7;
  const int x = wg & 7, p = wg >> 3;
  return (x < r ? x * (q + 1) : r * (q + 1) + (x - r) * q) + p;
}

// ---------------- zero fill (f16x8) ----------------
__global__ __launch_bounds__(256) void zero_kernel(f16* __restrict__ p, size_t n8) {
  const size_t i = (size_t)blockIdx.x * 256 + threadIdx.x;
  if (i < n8) reinterpret_cast<f16x8*>(p)[i] = f16x8{};
}

// ---------------- f32 -> f16 (padded, zero tail) ----------------
__global__ __launch_bounds__(256) void cvt_x_kernel(
    const float* __restrict__ xm, const float* __restrict__ xc,
    f16* __restrict__ ym, f16* __restrict__ yc) {
  const size_t i8 = ((size_t)blockIdx.x * 256 + threadIdx.x) * 8;
  f16x8 vm = {}, vc = {};
  if (i8 < (size_t)M * HID) {
    const float4 a0 = *reinterpret_cast<const float4*>(xm + i8);
    const float4 a1 = *reinterpret_cast<const float4*>(xm + i8 + 4);
    const float4 b0 = *reinterpret_cast<const float4*>(xc + i8);
    const float4 b1 = *reinterpret_cast<const float4*>(xc + i8 + 4);
    vm[0] = (f16)a0.x; vm[1] = (f16)a0.y; vm[2] = (f16)a0.z; vm[3] = (f16)a0.w;
    vm[4] = (f16)a1.x; vm[5] = (f16)a1.y; vm[6] = (f16)a1.z; vm[7] = (f16)a1.w;
    vc[0] = (f16)b0.x; vc[1] = (f16)b0.y; vc[2] = (f16)b0.z; vc[3] = (f16)b0.w;
    vc[4] = (f16)b1.x; vc[5] = (f16)b1.y; vc[6] = (f16)b1.z; vc[7] = (f16)b1.w;
  }
  *reinterpret_cast<f16x8*>(ym + i8) = vm;
  *reinterpret_cast<f16x8*>(yc + i8) = vc;
}

// ---------------- W [k][n] f32 -> Wt [n][k] f16 ----------------
struct WPtrs { const float* w[8]; };

__global__ __launch_bounds__(256) void cvt_w_kernel(WPtrs p, f16* __restrict__ wt) {
  __shared__ float tile[32][33];
  const int z = blockIdx.z;
  const float* W = p.w[z];
  f16* Wt = wt + (size_t)z * WSZ1;
  const int k0 = blockIdx.x * 32, n0 = blockIdx.y * 32;
  const int tx = threadIdx.x & 31, ty = threadIdx.x >> 5;
#pragma unroll
  for (int i = 0; i < 4; ++i)
    tile[ty + i * 8][tx] = W[(size_t)(k0 + ty + i * 8) * HID + n0 + tx];
  __syncthreads();
#pragma unroll
  for (int i = 0; i < 4; ++i)
    Wt[(size_t)(n0 + ty + i * 8) * HID + k0 + tx] = (f16)tile[tx][ty + i * 8];
}

// ---------------- shared MFMA GEMM core (128x128 tile, K=768) -------------
// global_load_lds staging, linear LDS + inverse-swizzled source, dbuf
__device__ __forceinline__ void gemm_core(
    const f16* __restrict__ Abase, const f16* __restrict__ Btbase,
    int m0, int n0, int tid, char (*lds)[16384], f32x4 (&acc)[4][4]) {
  const int w = tid >> 6, lane = tid & 63;
  const int l15 = lane & 15, lg = lane >> 4;
  const int wr = (w >> 1) * 64, wc = (w & 1) * 64;
  const int srow = w * 32 + (lane >> 3);
  const int scb = ((lane & 7) * 16) ^ ((srow & 7) << 4);
  const char* gA = reinterpret_cast<const char*>(Abase + (size_t)(m0 + srow) * HID) + scb;
  const char* gB = reinterpret_cast<const char*>(Btbase + (size_t)(n0 + srow) * HID) + scb;

  // prologue: stage kt=0 into buf0
#pragma unroll
  for (int i = 0; i < 4; ++i) {
    gload16(gA + (size_t)i * 8 * 1536, lds[0] + w * 4096 + i * 1024);
    gload16(gB + (size_t)i * 8 * 1536, lds[1] + w * 4096 + i * 1024);
  }
  __syncthreads();

  int cur = 0;
  for (int kt = 0; kt < 12; ++kt) {
    if (kt + 1 < 12) {  // stage next tile into other buffer (overlaps MFMA)
      const size_t off = (size_t)(kt + 1) * 128;
#pragma unroll
      for (int i = 0; i < 4; ++i) {
        gload16(gA + off + (size_t)i * 8 * 1536, lds[2 - 2 * cur] + w * 4096 + i * 1024);
        gload16(gB + off + (size_t)i * 8 * 1536, lds[3 - 2 * cur] + w * 4096 + i * 1024);
      }
    }
    const char* cA = lds[2 * cur];
    const char* cB = lds[2 * cur + 1];
#pragma unroll
    for (int ks = 0; ks < 2; ++ks) {
      f16x8 af[4], bf[4];
#pragma unroll
      for (int fi = 0; fi < 4; ++fi) {
        const int row = wr + l15 + fi * 16;
        af[fi] = *reinterpret_cast<const f16x8*>(
            cA + row * 128 + ((ks * 64 + lg * 16) ^ ((row & 7) << 4)));
      }
#pragma unroll
      for (int fj = 0; fj < 4; ++fj) {
        const int row = wc + l15 + fj * 16;
        bf[fj] = *reinterpret_cast<const f16x8*>(
            cB + row * 128 + ((ks * 64 + lg * 16) ^ ((row & 7) << 4)));
      }
#pragma unroll
      for (int fi = 0; fi < 4; ++fi)
#pragma unroll
        for (int fj = 0; fj < 4; ++fj)
          acc[fi][fj] = mfma16(af[fi], bf[fj], acc[fi][fj]);
    }
    __syncthreads();  // drains gload (vmcnt0) + protects dbuf swap
    cur ^= 1;
  }
}

// ---------------- projection GEMMs (z=0 mean, z=1 cov) ----------------
struct ProjArgs {
  const f16* A[2]; const f16* Bt[2];
  const float* bias[2][3];
  f16* out0[2];  // nsel 0: mq / sq   (scaled 0.5)
  f16* out1[2];  // nsel 1: mk / sk   (scaled 0.5)
  f16* vt[2];    // nsel 2: Vt mean / cov (transposed, unscaled)
};

__global__ __launch_bounds__(256, 2) void gemm_proj(ProjArgs g) {
  __shared__ char lds[4][16384];
  const int swz = xcd_swizzle(blockIdx.x, 99 * 18 * 2);
  const int x = swz % 99;
  const int t = swz / 99;
  const int y = t % 18, z = t / 18;
  const int m0 = x * 128, n0 = y * 128;

  f32x4 acc[4][4] = {};
  gemm_core(g.A[z], g.Bt[z], m0, n0, threadIdx.x, lds, acc);

  const int tid = threadIdx.x, w = tid >> 6, lane = tid & 63;
  const int l15 = lane & 15, lg = lane >> 4;
  const int wr = (w >> 1) * 64, wc = (w & 1) * 64;
  const int nsel = n0 / 768;
  const int ncol0 = (n0 - nsel * 768) + wc + l15;
  const int rbase = m0 + wr + lg * 4;
  const float* bias = g.bias[z][nsel];

  if (nsel < 2) {
    f16* Y = nsel ? g.out1[z] : g.out0[z];
#pragma unroll
    for (int fj = 0; fj < 4; ++fj) {
      const int col = ncol0 + fj * 16;
      const float bv = bias[col];
#pragma unroll
      for (int fi = 0; fi < 4; ++fi)
#pragma unroll
        for (int r = 0; r < 4; ++r) {
          const int row = rbase + fi * 16 + r;
          float v = acc[fi][fj][r] + bv;
          if (z == 1) { v = (v > 0.f) ? v + 1.f : __expf(v); v = sqrtf(v); }
          Y[(size_t)row * HID + col] = (f16)(v * 0.5f);
        }
    }
  } else {
    f16* VT = g.vt[z];
#pragma unroll
    for (int fj = 0; fj < 4; ++fj) {
      const int col = ncol0 + fj * 16;
      const float bv = bias[col];
      const int h = col >> 6, d = col & 63;
#pragma unroll
      for (int fi = 0; fi < 4; ++fi)
#pragma unroll
        for (int r = 0; r < 4; ++r) {
          const int row = rbase + fi * 16 + r;
          if (row < M) {
            float v = acc[fi][fj][r] + bv;
            if (z == 1) v = (v > 0.f) ? v + 1.f : __expf(v);
            const int bb = row / S, ss = row - bb * S;
            VT[((size_t)(bb * NH + h) * DH + d) * VSTRIDE + ss] = (f16)v;
          }
        }
    }
  }
}

// ---------------- output GEMMs (z=0 mean, z=1 cov), f32 out ---------------
struct OutArgs {
  const f16* A[2]; const f16* Bt[2]; const float* bias[2]; float* Y[2];
};

__global__ __launch_bounds__(256, 2) void gemm_out(OutArgs g) {
  __shared__ char lds[4][16384];
  const int swz = xcd_swizzle(blockIdx.x, 99 * 6 * 2);
  const int x = swz % 99;
  const int t = swz / 99;
  const int y = t % 6, z = t / 6;
  const int m0 = x * 128, n0 = y * 128;

  f32x4 acc[4][4] = {};
  gemm_core(g.A[z], g.Bt[z], m0, n0, threadIdx.x, lds, acc);

  const int tid = threadIdx.x, w = tid >> 6, lane = tid & 63;
  const int l15 = lane & 15, lg = lane >> 4;
  const int wr = (w >> 1) * 64, wc = (w & 1) * 64;
  const int rbase = m0 + wr + lg * 4;
  float* Y = g.Y[z];
#pragma unroll
  for (int fj = 0; fj < 4; ++fj) {
    const int col = n0 + wc + l15 + fj * 16;
    const float bv = g.bias[z][col];
#pragma unroll
    for (int fi = 0; fi < 4; ++fi)
#pragma unroll
      for (int r = 0; r < 4; ++r) {
        const int row = rbase + fi * 16 + r;
        if (row < M) Y[(size_t)row * HID + col] = acc[fi][fj][r] + bv;
      }
  }
}

// -------- per-(b,h,s) terms (inputs pre-scaled by 0.5) --------
// qterm = 0.125*sum(m^2 + s^2) given stored 0.5m, 0.5s
__global__ __launch_bounds__(256) void sums_kernel(
    const f16* __restrict__ mq, const f16* __restrict__ sq,
    const f16* __restrict__ mk, const f16* __restrict__ sk,
    float* __restrict__ qterm, float* __restrict__ kterm) {
  const int w = threadIdx.x >> 6, lane = threadIdx.x & 63;
  const int t = blockIdx.x * 4 + w;
  const int b = t / (NH * S);
  const int rem = t - b * (NH * S);
  const int h = rem / S;
  const int s = rem - h * S;
  const size_t idx = (size_t)(b * S + s) * HID + h * DH + lane;
  const float a1 = (float)mq[idx], a2 = (float)sq[idx];
  const float a3 = (float)mk[idx], a4 = (float)sk[idx];
  float vq = a1 * a1 + a2 * a2;
  float vk = a3 * a3 + a4 * a4;
#pragma unroll
  for (int off = 32; off; off >>= 1) {
    vq += __shfl_down(vq, off, 64);
    vk += __shfl_down(vk, off, 64);
  }
  if (lane == 0) { qterm[t] = 0.5f * vq; kterm[t] = 0.5f * vk; }
}

// ---------------- fused Wasserstein attention ----------------
// block = (b,h,64-row Q tile); swapped QK^T (K as A-operand) so each lane
// holds 4 contiguous j -> b64 P writes; V read pre-transposed from global.
__global__ __launch_bounds__(256, 2) void attn_kernel(
    const f16* __restrict__ mq, const f16* __restrict__ sq,
    const f16* __restrict__ mk, const f16* __restrict__ sk,
    const f16* __restrict__ vtm, const f16* __restrict__ vtc,
    const float* __restrict__ qterm, const float* __restrict__ kterm,
    f16* __restrict__ mean_ctx, f16* __restrict__ cov_ctx) {
  __shared__ char Pb[64 * 512];  // P[q][j] f16, XOR-swizzled rows
  __shared__ float qt_s[64];
  __shared__ float kt_s[256];
  __shared__ float red_m[4][64];
  __shared__ float red_s[4][64];

  const int swz = xcd_swizzle(blockIdx.x, 3072);
  const int qtile = swz & 3, bh = swz >> 2;
  const int h = bh % NH, b = bh / NH;
  const int s0 = qtile * 64;
  const int tid = threadIdx.x, w = tid >> 6, lane = tid & 63;
  const int l15 = lane & 15, lg = lane >> 4;

  const size_t base = (size_t)(b * S) * HID + (size_t)h * DH;
  const int tb = bh * S;

  // Q fragments (B-operand): row = s0+fi*16+l15, k = lg*8 (+32)
  f16x8 qmf[4][2], qsf[4][2];
#pragma unroll
  for (int fi = 0; fi < 4; ++fi) {
    const size_t o = base + (size_t)(s0 + fi * 16 + l15) * HID + lg * 8;
    qmf[fi][0] = *reinterpret_cast<const f16x8*>(mq + o);
    qmf[fi][1] = *reinterpret_cast<const f16x8*>(mq + o + 32);
    qsf[fi][0] = *reinterpret_cast<const f16x8*>(sq + o);
    qsf[fi][1] = *reinterpret_cast<const f16x8*>(sq + o + 32);
  }
  if (tid < 64) qt_s[tid] = (s0 + tid < S) ? qterm[tb + s0 + tid] : 0.f;
  kt_s[tid] = (tid < S) ? kterm[tb + tid] : 0.f;
  __syncthreads();

  // scores^T: acc[fj][fi], rows = K tokens (wave-owned 64), cols = Q tokens
  f32x4 acc[4][4] = {};
#pragma unroll
  for (int fj = 0; fj < 4; ++fj) {
    const size_t o = base + (size_t)(w * 64 + fj * 16 + l15) * HID + lg * 8;
    const f16x8 a0 = *reinterpret_cast<const f16x8*>(mk + o);
    const f16x8 a1 = *reinterpret_cast<const f16x8*>(mk + o + 32);
    const f16x8 c0 = *reinterpret_cast<const f16x8*>(sk + o);
    const f16x8 c1 = *reinterpret_cast<const f16x8*>(sk + o + 32);
#pragma unroll
    for (int fi = 0; fi < 4; ++fi) {
      acc[fj][fi] = mfma16(a0, qmf[fi][0], acc[fj][fi]);
      acc[fj][fi] = mfma16(c0, qsf[fi][0], acc[fj][fi]);
      acc[fj][fi] = mfma16(a1, qmf[fi][1], acc[fj][fi]);
      acc[fj][fi] = mfma16(c1, qsf[fi][1], acc[fj][fi]);
    }
  }

  // transform + wave-partial row max (reduce over j: lanes differing in lg)
#pragma unroll
  for (int fi = 0; fi < 4; ++fi) {
    const float qv = qt_s[fi * 16 + l15];
    float mx = -1e30f;
#pragma unroll
    for (int fj = 0; fj < 4; ++fj)
#pragma unroll
      for (int r = 0; r < 4; ++r) {
        const int j = w * 64 + fj * 16 + lg * 4 + r;
        float sv = acc[fj][fi][r] - qv - kt_s[j];
        if (j >= S) sv = -1e30f;
        acc[fj][fi][r] = sv;
        mx = fmaxf(mx, sv);
      }
    mx = fmaxf(mx, __shfl_xor(mx, 16, 64));
    mx = fmaxf(mx, __shfl_xor(mx, 32, 64));
    if (lg == 0) red_m[w][fi * 16 + l15] = mx;
  }
  __syncthreads();

  // exp (unnormalized) -> P (b64 writes), partial sums
#pragma unroll
  for (int fi = 0; fi < 4; ++fi) {
    const int q = fi * 16 + l15;
    const float m = fmaxf(fmaxf(red_m[0][q], red_m[1][q]),
                          fmaxf(red_m[2][q], red_m[3][q]));
    const int xr = (q & 7) << 4;
    float sum = 0.f;
#pragma unroll
    for (int fj = 0; fj < 4; ++fj) {
      f16x4 p4;
#pragma unroll
      for (int r = 0; r < 4; ++r) {
        const float e = __expf(acc[fj][fi][r] - m);
        sum += e;
        p4[r] = (f16)e;
      }
      *reinterpret_cast<f16x4*>(
          Pb + q * 512 + ((2 * (w * 64 + fj * 16 + lg * 4)) ^ xr)) = p4;
    }
    sum += __shfl_xor(sum, 16, 64);
    sum += __shfl_xor(sum, 32, 64);
    if (lg == 0) red_s[w][q] = sum;
  }
  __syncthreads();

  // PV: A = P rows (q), B = Vt rows (d) direct from global
  const int d = w * 16 + l15;
  const size_t vbase = ((size_t)bh * DH + d) * VSTRIDE + lg * 8;
  f32x4 macc[4] = {}, cacc[4] = {};
#pragma unroll
  for (int ks = 0; ks < 7; ++ks) {
    const f16x8 vm = *reinterpret_cast<const f16x8*>(vtm + vbase + ks * 32);
    const f16x8 vc = *reinterpret_cast<const f16x8*>(vtc + vbase + ks * 32);
#pragma unroll
    for (int fi = 0; fi < 4; ++fi) {
      const int q = fi * 16 + l15;
      const f16x8 pa = *reinterpret_cast<const f16x8*>(
          Pb + q * 512 + ((2 * (ks * 32 + lg * 8)) ^ ((q & 7) << 4)));
      macc[fi] = mfma16(pa, vm, macc[fi]);
      const f16x8 pq = pa * pa;
      cacc[fi] = mfma16(pq, vc, cacc[fi]);
    }
  }

  // epilogue: normalize by row sums
#pragma unroll
  for (int fi = 0; fi < 4; ++fi)
#pragma unroll
    for (int r = 0; r < 4; ++r) {
      const int qo = fi * 16 + lg * 4 + r;
      const int srow = s0 + qo;
      if (srow < S) {
        const float tot = red_s[0][qo] + red_s[1][qo] + red_s[2][qo] + red_s[3][qo];
        const float inv = 1.f / tot;
        const size_t oidx = (size_t)(b * S + srow) * HID + h * DH + d;
        mean_ctx[oidx] = (f16)(macc[fi][r] * inv);
        cov_ctx[oidx] = (f16)(cacc[fi][r] * inv * inv);
      }
    }
}

extern "C" void kernel_launch(void* const* d_in, const int* in_sizes, int n_in,
                              void* d_out, int out_size, void* d_ws, size_t ws_size,
                              hipStream_t stream) {
  const float* in_mean = (const float*)d_in[0];
  const float* in_cov = (const float*)d_in[1];
  const float* Wmq = (const float*)d_in[2];  const float* bmq = (const float*)d_in[3];
  const float* Wcq = (const float*)d_in[4];  const float* bcq = (const float*)d_in[5];
  const float* Wmk = (const float*)d_in[6];  const float* bmk = (const float*)d_in[7];
  const float* Wck = (const float*)d_in[8];  const float* bck = (const float*)d_in[9];
  const float* Wmv = (const float*)d_in[10]; const float* bmv = (const float*)d_in[11];
  const float* Wcv = (const float*)d_in[12]; const float* bcv = (const float*)d_in[13];
  const float* Wmd = (const float*)d_in[14]; const float* bmd = (const float*)d_in[15];
  const float* Wcd = (const float*)d_in[16]; const float* bcd = (const float*)d_in[17];

  const size_t need = (6 * NPH + 8 * WSZ1 + 2 * VTSZ) * sizeof(f16) +
                      2 * (size_t)BNS * sizeof(float);
  if (ws_size < need) return;

  f16* Xm = (f16*)d_ws;          // later: mean_ctx
  f16* Xc = Xm + NPH;            // later: cov_ctx
  f16* Wt = Xc + NPH;
  f16* mq = Wt + 8 * WSZ1;
  f16* mk = mq + NPH;
  f16* sq = mk + NPH;
  f16* sk = sq + NPH;
  f16* vtm = sk + NPH;
  f16* vtc = vtm + VTSZ;
  float* qterm = (float*)(vtc + VTSZ);
  float* kterm = qterm + BNS;
  f16* mean_ctx = Xm;
  f16* cov_ctx = Xc;

  float* out_mean = (float*)d_out;
  float* out_cov = out_mean + (size_t)M * HID;

  dim3 blk(256);

  zero_kernel<<<(2 * VTSZ / 8 + 255) / 256, blk, 0, stream>>>(vtm, 2 * VTSZ / 8);
  cvt_x_kernel<<<NPH / 2048, blk, 0, stream>>>(in_mean, in_cov, Xm, Xc);

  WPtrs wp;
  wp.w[0] = Wmq; wp.w[1] = Wmk; wp.w[2] = Wmv;
  wp.w[3] = Wcq; wp.w[4] = Wck; wp.w[5] = Wcv;
  wp.w[6] = Wmd; wp.w[7] = Wcd;
  cvt_w_kernel<<<dim3(24, 24, 8), blk, 0, stream>>>(wp, Wt);

  ProjArgs pa;
  pa.A[0] = Xm; pa.A[1] = Xc;
  pa.Bt[0] = Wt; pa.Bt[1] = Wt + 3 * WSZ1;
  pa.bias[0][0] = bmq; pa.bias[0][1] = bmk; pa.bias[0][2] = bmv;
  pa.bias[1][0] = bcq; pa.bias[1][1] = bck; pa.bias[1][2] = bcv;
  pa.out0[0] = mq; pa.out0[1] = sq;
  pa.out1[0] = mk; pa.out1[1] = sk;
  pa.vt[0] = vtm; pa.vt[1] = vtc;
  gemm_proj<<<99 * 18 * 2, blk, 0, stream>>>(pa);

  sums_kernel<<<BNS / 4, blk, 0, stream>>>(mq, sq, mk, sk, qterm, kterm);

  attn_kernel<<<3072, blk, 0, stream>>>(mq, sq, mk, sk, vtm, vtc,
                                        qterm, kterm, mean_ctx, cov_ctx);

  OutArgs oa;
  oa.A[0] = mean_ctx; oa.A[1] = cov_ctx;
  oa.Bt[0] = Wt + 6 * WSZ1; oa.Bt[1] = Wt + 7 * WSZ1;
  oa.bias[0] = bmd; oa.bias[1] = bcd;
  oa.Y[0] = out_mean; oa.Y[1] = out_cov;
  gemm_out<<<99 * 6 * 2, blk, 0, stream>>>(oa);
}